// Round 2
// baseline (448.963 us; speedup 1.0000x reference)
//
#include <hip/hip_runtime.h>

#define BB 8
#define SS 512
#define HH 1024
#define NHH 16
#define HDD 64

typedef short short8 __attribute__((ext_vector_type(8)));
typedef float f32x4 __attribute__((ext_vector_type(4)));

// ---------------------------------------------------------------------------
// split one fp32 pair into packed bf16 hi (truncated) + bf16 lo (residual,
// truncated).  hi/lo each hold 2 bf16 lanes: [f1:f0].
// error after Ah*Bh + Ah*Bl + Al*Bh reconstruction ~ 2^-14 relative.
// ---------------------------------------------------------------------------
__device__ __forceinline__ void split2(float f0, float f1,
                                       unsigned& hi, unsigned& lo)
{
    unsigned u0 = __builtin_bit_cast(unsigned, f0);
    unsigned u1 = __builtin_bit_cast(unsigned, f1);
    hi = __builtin_amdgcn_perm(u1, u0, 0x07060302u);   // [u1.hi16 : u0.hi16]
    float r0 = f0 - __builtin_bit_cast(float, u0 & 0xffff0000u);
    float r1 = f1 - __builtin_bit_cast(float, u1 & 0xffff0000u);
    unsigned v0 = __builtin_bit_cast(unsigned, r0);
    unsigned v1 = __builtin_bit_cast(unsigned, r1);
    lo = __builtin_amdgcn_perm(v1, v0, 0x07060302u);
}

// ---------------------------------------------------------------------------
// Kernel 1: fused QKV projection via split-bf16 MFMA.
//   C[4096 x 3072] = HS[4096 x 1024] @ [Wq|Wk|Wv]^T + bias, scattered to
//   three [B,NH,S,HD] tensors.  128x128 tile, BK=32, 256 thr (4 waves 2x2).
// ---------------------------------------------------------------------------
__global__ __launch_bounds__(256)
void qkv_proj_kernel(const float* __restrict__ HS,
                     const float* __restrict__ Wq, const float* __restrict__ bq,
                     const float* __restrict__ Wk, const float* __restrict__ bk,
                     const float* __restrict__ Wv, const float* __restrict__ bv,
                     float* __restrict__ Qo, float* __restrict__ Ko, float* __restrict__ Vo)
{
    const int bx = blockIdx.x;            // 0..23  (n tiles, 8 per matrix)
    const int by = blockIdx.y;            // 0..31  (m tiles)
    const int z   = bx >> 3;              // which of Q/K/V
    const int nf0 = (bx & 7) * 128;       // feature offset inside the matrix
    const int m0  = by * 128;

    const float* W    = (z == 0) ? Wq : (z == 1) ? Wk : Wv;
    const float* bias = (z == 0) ? bq : (z == 1) ? bk : bv;
    float*       Out  = (z == 0) ? Qo : (z == 1) ? Ko : Vo;

    __shared__ short Ah[128][32];
    __shared__ short Al[128][32];
    __shared__ short Bh[128][32];
    __shared__ short Bl[128][32];

    const int tid  = threadIdx.x;
    const int lane = tid & 63;
    const int wave = tid >> 6;            // 0..3
    const int wm   = (wave & 1) * 64;     // wave m offset in tile
    const int wn   = (wave >> 1) * 64;    // wave n offset in tile

    // staging coords: each thread owns 16 consecutive k of one row
    const int srow = tid >> 1;            // 0..127
    const int skh  = (tid & 1) * 16;      // k offset 0/16

    // fragment coords
    const int fr    = lane & 15;          // m (A) / n (B) within 16
    const int kslot = lane >> 4;          // which 16B k-slot

    f32x4 acc[4][4];
#pragma unroll
    for (int i = 0; i < 4; i++)
#pragma unroll
        for (int j = 0; j < 4; j++) acc[i][j] = (f32x4)0.0f;

    for (int k0 = 0; k0 < HH; k0 += 32) {
        __syncthreads();   // previous chunk's reads done
        // ---- stage A (HS rows) and B (W rows), fp32 -> hi/lo bf16 ----
        {
            float ra[16], rb[16];
            const float* pa = HS + (size_t)(m0 + srow) * HH + k0 + skh;
            const float* pb = W + (size_t)(nf0 + srow) * HH + k0 + skh;
#pragma unroll
            for (int u = 0; u < 4; u++) {
                *(float4*)&ra[4 * u] = *(const float4*)(pa + 4 * u);
                *(float4*)&rb[4 * u] = *(const float4*)(pb + 4 * u);
            }
            unsigned ha[8], la[8], hb[8], lb[8];
#pragma unroll
            for (int p = 0; p < 8; p++) {
                split2(ra[2 * p], ra[2 * p + 1], ha[p], la[p]);
                split2(rb[2 * p], rb[2 * p + 1], hb[p], lb[p]);
            }
            *(uint4*)&Ah[srow][skh]     = *(uint4*)&ha[0];
            *(uint4*)&Ah[srow][skh + 8] = *(uint4*)&ha[4];
            *(uint4*)&Al[srow][skh]     = *(uint4*)&la[0];
            *(uint4*)&Al[srow][skh + 8] = *(uint4*)&la[4];
            *(uint4*)&Bh[srow][skh]     = *(uint4*)&hb[0];
            *(uint4*)&Bh[srow][skh + 8] = *(uint4*)&hb[4];
            *(uint4*)&Bl[srow][skh]     = *(uint4*)&lb[0];
            *(uint4*)&Bl[srow][skh + 8] = *(uint4*)&lb[4];
        }
        __syncthreads();

        // ---- fragments + 48 MFMAs ----
        short8 a_h[4], a_l[4], b_h[4], b_l[4];
#pragma unroll
        for (int i = 0; i < 4; i++) {
            a_h[i] = *(const short8*)&Ah[wm + i * 16 + fr][kslot * 8];
            a_l[i] = *(const short8*)&Al[wm + i * 16 + fr][kslot * 8];
            b_h[i] = *(const short8*)&Bh[wn + i * 16 + fr][kslot * 8];
            b_l[i] = *(const short8*)&Bl[wn + i * 16 + fr][kslot * 8];
        }
#pragma unroll
        for (int i = 0; i < 4; i++)
#pragma unroll
            for (int j = 0; j < 4; j++) {
                acc[i][j] = __builtin_amdgcn_mfma_f32_16x16x32_bf16(a_h[i], b_h[j], acc[i][j], 0, 0, 0);
                acc[i][j] = __builtin_amdgcn_mfma_f32_16x16x32_bf16(a_h[i], b_l[j], acc[i][j], 0, 0, 0);
                acc[i][j] = __builtin_amdgcn_mfma_f32_16x16x32_bf16(a_l[i], b_h[j], acc[i][j], 0, 0, 0);
            }
    }

    // ---- epilogue: C/D layout col=lane&15, row=(lane>>4)*4+reg ----
    const int cn  = lane & 15;
    const int rm4 = (lane >> 4) * 4;
#pragma unroll
    for (int j = 0; j < 4; j++) {
        const int nn = nf0 + wn + j * 16 + cn;     // feature 0..1023
        const int h  = nn >> 6;
        const int hd = nn & 63;
        const float bval = bias[nn];
#pragma unroll
        for (int i = 0; i < 4; i++) {
            const int mmb = m0 + wm + i * 16 + rm4;
            const int bi  = mmb >> 9;
            const int s0  = mmb & 511;
            float* base = Out + (((size_t)(bi * NHH + h) * SS + s0) * HDD + hd);
#pragma unroll
            for (int r = 0; r < 4; r++)
                base[(size_t)r * HDD] = acc[i][j][r] + bval;
        }
    }
}

// ---------------------------------------------------------------------------
// Kernel 2: attention with relative_key bias (fp32 VALU), unchanged round-0
// design: block = (64-row q-tile, head, batch), 256 threads, streamed 64-wide
// K/V tiles, banded dist_emb, no online max (logits bounded).
// ---------------------------------------------------------------------------
__global__ __launch_bounds__(256)
void attn_kernel(const float* __restrict__ Q, const float* __restrict__ K,
                 const float* __restrict__ V, const float* __restrict__ mask,
                 const float* __restrict__ demb, float* __restrict__ out)
{
    const int qt  = blockIdx.x;   // 0..7
    const int h   = blockIdx.y;   // 0..15
    const int b   = blockIdx.z;   // 0..7
    const int l0  = qt * 64;
    const int tid = threadIdx.x;

    __shared__ float Qt[64][68];    // [d][l], pre-scaled by 1/8
    __shared__ float Kt[64][68];    // [d][r]
    __shared__ float Et[64][132];   // [d][j], banded dist rows
    __shared__ float Vs[64][68];    // [r][d]
    __shared__ float Pt[64][68];    // logits -> probs ; reused for sums
    __shared__ float Ms[64];

    const size_t bh = (size_t)(b * NHH + h) * SS;
    const float* Qb = Q + bh * HDD;
    const float* Kb = K + bh * HDD;
    const float* Vb = V + bh * HDD;

    {
        const int l = tid >> 2, dc = (tid & 3) * 16;
        const float* src = Qb + (size_t)(l0 + l) * HDD + dc;
#pragma unroll
        for (int u = 0; u < 4; u++) {
            float4 v = *(const float4*)(src + 4 * u);
            Qt[dc + 4*u + 0][l] = v.x * 0.125f;
            Qt[dc + 4*u + 1][l] = v.y * 0.125f;
            Qt[dc + 4*u + 2][l] = v.z * 0.125f;
            Qt[dc + 4*u + 3][l] = v.w * 0.125f;
        }
    }

    const int lq  = tid & 15, rq = tid >> 4;
    const int li0 = lq * 4, ri0 = rq * 4;
    const int jbb = li0 - ri0 + 60;
    const int g3  = tid >> 4;
    const int tx  = tid & 15;

    float o[4][4];
#pragma unroll
    for (int i = 0; i < 4; i++)
#pragma unroll
        for (int u = 0; u < 4; u++) o[i][u] = 0.f;
    float s_part[4] = {0.f, 0.f, 0.f, 0.f};

    for (int rt = 0; rt < 8; rt++) {
        const int r0 = rt * 64;
        __syncthreads();

        {
            const int r = tid >> 2, dc = (tid & 3) * 16;
            const float* srck = Kb + (size_t)(r0 + r) * HDD + dc;
            const float* srcv = Vb + (size_t)(r0 + r) * HDD + dc;
#pragma unroll
            for (int u = 0; u < 4; u++) {
                float4 kv = *(const float4*)(srck + 4 * u);
                Kt[dc + 4*u + 0][r] = kv.x;
                Kt[dc + 4*u + 1][r] = kv.y;
                Kt[dc + 4*u + 2][r] = kv.z;
                Kt[dc + 4*u + 3][r] = kv.w;
                *(float4*)&Vs[r][dc + 4 * u] = *(const float4*)(srcv + 4 * u);
            }
        }
        {
            const int jrow = tid >> 1, dc2 = (tid & 1) * 32;
            if (jrow < 127) {
                const int jb0 = l0 - r0 + 448;
                const float* src = demb + (size_t)(jb0 + jrow) * HDD + dc2;
#pragma unroll
                for (int u = 0; u < 8; u++) {
                    float4 v = *(const float4*)(src + 4 * u);
                    Et[dc2 + 4*u + 0][jrow] = v.x;
                    Et[dc2 + 4*u + 1][jrow] = v.y;
                    Et[dc2 + 4*u + 2][jrow] = v.z;
                    Et[dc2 + 4*u + 3][jrow] = v.w;
                }
            }
        }
        if (tid < 64) Ms[tid] = mask[(size_t)b * SS + r0 + tid];
        __syncthreads();

        float acc[4][4];
#pragma unroll
        for (int i = 0; i < 4; i++)
#pragma unroll
            for (int p = 0; p < 4; p++) acc[i][p] = 0.f;

#pragma unroll 4
        for (int d = 0; d < 64; d++) {
            float qv[4], kv[4], ee[8];
            *(float4*)&qv[0] = *(const float4*)&Qt[d][li0];
            *(float4*)&kv[0] = *(const float4*)&Kt[d][ri0];
            *(float4*)&ee[0] = *(const float4*)&Et[d][jbb];
            *(float4*)&ee[4] = *(const float4*)&Et[d][jbb + 4];
#pragma unroll
            for (int i = 0; i < 4; i++)
#pragma unroll
                for (int p = 0; p < 4; p++)
                    acc[i][p] += qv[i] * (kv[p] + ee[3 + i - p]);
        }
#pragma unroll
        for (int i = 0; i < 4; i++) {
            float4 w;
            w.x = acc[i][0] + Ms[ri0 + 0];
            w.y = acc[i][1] + Ms[ri0 + 1];
            w.z = acc[i][2] + Ms[ri0 + 2];
            w.w = acc[i][3] + Ms[ri0 + 3];
            *(float4*)&Pt[li0 + i][ri0] = w;
        }
        __syncthreads();

#pragma unroll
        for (int i = 0; i < 4; i++) {
            float4 p = *(float4*)&Pt[4*g3 + i][4*tx];
            p.x = __expf(p.x); p.y = __expf(p.y);
            p.z = __expf(p.z); p.w = __expf(p.w);
            *(float4*)&Pt[4*g3 + i][4*tx] = p;
            s_part[i] += p.x + p.y + p.z + p.w;
        }
        __syncthreads();

#pragma unroll 2
        for (int rr = 0; rr < 64; rr += 4) {
            float pr[4][4], vv[4][4];
#pragma unroll
            for (int i = 0; i < 4; i++)
                *(float4*)&pr[i][0] = *(const float4*)&Pt[4*g3 + i][rr];
#pragma unroll
            for (int j = 0; j < 4; j++)
                *(float4*)&vv[j][0] = *(const float4*)&Vs[rr + j][4 * tx];
#pragma unroll
            for (int i = 0; i < 4; i++)
#pragma unroll
                for (int j = 0; j < 4; j++)
#pragma unroll
                    for (int u = 0; u < 4; u++)
                        o[i][u] += pr[i][j] * vv[j][u];
        }
    }

    __syncthreads();
#pragma unroll
    for (int i = 0; i < 4; i++)
        Pt[tx][4*g3 + i] = s_part[i];
    __syncthreads();
#pragma unroll
    for (int i = 0; i < 4; i++) {
        float s = 0.f;
#pragma unroll
        for (int t = 0; t < 16; t++) s += Pt[t][4*g3 + i];
        const float inv = 1.f / s;
        const int l = l0 + 4*g3 + i;
        float4 r;
        r.x = o[i][0] * inv; r.y = o[i][1] * inv;
        r.z = o[i][2] * inv; r.w = o[i][3] * inv;
        *(float4*)(out + ((size_t)b * SS + l) * HH + h * HDD + 4 * tx) = r;
    }
}

// ---------------------------------------------------------------------------
extern "C" void kernel_launch(void* const* d_in, const int* in_sizes, int n_in,
                              void* d_out, int out_size, void* d_ws, size_t ws_size,
                              hipStream_t stream)
{
    const float* HS   = (const float*)d_in[0];
    const float* mask = (const float*)d_in[1];
    const float* Wq   = (const float*)d_in[2];
    const float* bq   = (const float*)d_in[3];
    const float* Wk   = (const float*)d_in[4];
    const float* bk   = (const float*)d_in[5];
    const float* Wv   = (const float*)d_in[6];
    const float* bv   = (const float*)d_in[7];
    const float* demb = (const float*)d_in[8];
    float* out = (float*)d_out;

    const size_t per = (size_t)BB * NHH * SS * HDD;  // 4,194,304 floats
    float* Qw = (float*)d_ws;
    float* Kw = Qw + per;
    float* Vw = Kw + per;

    dim3 gp(24, 32);                         // n-tiles (8 per matrix) x m-tiles
    qkv_proj_kernel<<<gp, 256, 0, stream>>>(HS, Wq, bq, Wk, bk, Wv, bv, Qw, Kw, Vw);

    dim3 ga(SS / 64, NHH, BB);               // (8, 16, 8)
    attn_kernel<<<ga, 256, 0, stream>>>(Qw, Kw, Vw, mask, demb, out);
}

// Round 5
// 276.895 us; speedup vs baseline: 1.6214x; 1.6214x over previous
//
#include <hip/hip_runtime.h>

#define BB 8
#define SS 512
#define HH 1024
#define NHH 16
#define HDD 64

typedef short short8 __attribute__((ext_vector_type(8)));
typedef float f32x4 __attribute__((ext_vector_type(4)));

union U4S8 { unsigned u[4]; short8 s; uint4 v; };

// split fp32 pair -> packed bf16 hi (trunc) + bf16 lo (residual, trunc).
// A*B ~= Ah*Bh + Ah*Bl + Al*Bh with ~2^-17 relative error.
__device__ __forceinline__ void split2(float f0, float f1,
                                       unsigned& hi, unsigned& lo)
{
    unsigned u0 = __builtin_bit_cast(unsigned, f0);
    unsigned u1 = __builtin_bit_cast(unsigned, f1);
    hi = __builtin_amdgcn_perm(u1, u0, 0x07060302u);   // [bf16(f1) : bf16(f0)]
    float r0 = f0 - __builtin_bit_cast(float, u0 & 0xffff0000u);
    float r1 = f1 - __builtin_bit_cast(float, u1 & 0xffff0000u);
    unsigned v0 = __builtin_bit_cast(unsigned, r0);
    unsigned v1 = __builtin_bit_cast(unsigned, r1);
    lo = __builtin_amdgcn_perm(v1, v0, 0x07060302u);
}

__device__ __forceinline__ unsigned short bf16_rne(float f) {
    unsigned u = __builtin_bit_cast(unsigned, f);
    u += 0x7fffu + ((u >> 16) & 1u);
    return (unsigned short)(u >> 16);
}
__device__ __forceinline__ unsigned short bf16_tr(float f) {
    return (unsigned short)(__builtin_bit_cast(unsigned, f) >> 16);
}
__device__ __forceinline__ float bf16f(unsigned short s) {
    unsigned u = ((unsigned)s) << 16;
    return __builtin_bit_cast(float, u);
}
// element index into a swizzled [64][64] bf16 tile (rows stride 128 B);
// 16B-granule XOR by row&7 kills the stride-128 bank conflict (G4).
__device__ __forceinline__ int swel(int row, int col) {
    return row * 64 + ((((col >> 3) ^ (row & 7)) << 3) | (col & 7));
}

// ---------------------------------------------------------------------------
// Kernel 1: fused QKV projection via split-bf16 MFMA (validated in R2).
// ---------------------------------------------------------------------------
__global__ __launch_bounds__(256)
void qkv_proj_kernel(const float* __restrict__ HS,
                     const float* __restrict__ Wq, const float* __restrict__ bq,
                     const float* __restrict__ Wk, const float* __restrict__ bk,
                     const float* __restrict__ Wv, const float* __restrict__ bv,
                     float* __restrict__ Qo, float* __restrict__ Ko, float* __restrict__ Vo)
{
    const int bx = blockIdx.x;
    const int by = blockIdx.y;
    const int z   = bx >> 3;
    const int nf0 = (bx & 7) * 128;
    const int m0  = by * 128;

    const float* W    = (z == 0) ? Wq : (z == 1) ? Wk : Wv;
    const float* bias = (z == 0) ? bq : (z == 1) ? bk : bv;
    float*       Out  = (z == 0) ? Qo : (z == 1) ? Ko : Vo;

    __shared__ short Ah[128][32];
    __shared__ short Al[128][32];
    __shared__ short Bh[128][32];
    __shared__ short Bl[128][32];

    const int tid  = threadIdx.x;
    const int lane = tid & 63;
    const int wave = tid >> 6;
    const int wm   = (wave & 1) * 64;
    const int wn   = (wave >> 1) * 64;

    const int srow = tid >> 1;
    const int skh  = (tid & 1) * 16;

    const int fr    = lane & 15;
    const int kslot = lane >> 4;

    f32x4 acc[4][4];
#pragma unroll
    for (int i = 0; i < 4; i++)
#pragma unroll
        for (int j = 0; j < 4; j++) acc[i][j] = (f32x4)0.0f;

    for (int k0 = 0; k0 < HH; k0 += 32) {
        __syncthreads();
        {
            float ra[16], rb[16];
            const float* pa = HS + (size_t)(m0 + srow) * HH + k0 + skh;
            const float* pb = W + (size_t)(nf0 + srow) * HH + k0 + skh;
#pragma unroll
            for (int u = 0; u < 4; u++) {
                *(float4*)&ra[4 * u] = *(const float4*)(pa + 4 * u);
                *(float4*)&rb[4 * u] = *(const float4*)(pb + 4 * u);
            }
            unsigned ha[8], la[8], hb[8], lb[8];
#pragma unroll
            for (int p = 0; p < 8; p++) {
                split2(ra[2 * p], ra[2 * p + 1], ha[p], la[p]);
                split2(rb[2 * p], rb[2 * p + 1], hb[p], lb[p]);
            }
            *(uint4*)&Ah[srow][skh]     = *(uint4*)&ha[0];
            *(uint4*)&Ah[srow][skh + 8] = *(uint4*)&ha[4];
            *(uint4*)&Al[srow][skh]     = *(uint4*)&la[0];
            *(uint4*)&Al[srow][skh + 8] = *(uint4*)&la[4];
            *(uint4*)&Bh[srow][skh]     = *(uint4*)&hb[0];
            *(uint4*)&Bh[srow][skh + 8] = *(uint4*)&hb[4];
            *(uint4*)&Bl[srow][skh]     = *(uint4*)&lb[0];
            *(uint4*)&Bl[srow][skh + 8] = *(uint4*)&lb[4];
        }
        __syncthreads();

        short8 a_h[4], a_l[4], b_h[4], b_l[4];
#pragma unroll
        for (int i = 0; i < 4; i++) {
            a_h[i] = *(const short8*)&Ah[wm + i * 16 + fr][kslot * 8];
            a_l[i] = *(const short8*)&Al[wm + i * 16 + fr][kslot * 8];
            b_h[i] = *(const short8*)&Bh[wn + i * 16 + fr][kslot * 8];
            b_l[i] = *(const short8*)&Bl[wn + i * 16 + fr][kslot * 8];
        }
#pragma unroll
        for (int i = 0; i < 4; i++)
#pragma unroll
            for (int j = 0; j < 4; j++) {
                acc[i][j] = __builtin_amdgcn_mfma_f32_16x16x32_bf16(a_h[i], b_h[j], acc[i][j], 0, 0, 0);
                acc[i][j] = __builtin_amdgcn_mfma_f32_16x16x32_bf16(a_h[i], b_l[j], acc[i][j], 0, 0, 0);
                acc[i][j] = __builtin_amdgcn_mfma_f32_16x16x32_bf16(a_l[i], b_h[j], acc[i][j], 0, 0, 0);
            }
    }

    const int cn  = lane & 15;
    const int rm4 = (lane >> 4) * 4;
#pragma unroll
    for (int j = 0; j < 4; j++) {
        const int nn = nf0 + wn + j * 16 + cn;
        const int h  = nn >> 6;
        const int hd = nn & 63;
        const float bval = bias[nn];
#pragma unroll
        for (int i = 0; i < 4; i++) {
            const int mmb = m0 + wm + i * 16 + rm4;
            const int bi  = mmb >> 9;
            const int s0  = mmb & 511;
            float* base = Out + (((size_t)(bi * NHH + h) * SS + s0) * HDD + hd);
#pragma unroll
            for (int r = 0; r < 4; r++)
                base[(size_t)r * HDD] = acc[i][j][r] + bval;
        }
    }
}

// ---------------------------------------------------------------------------
// Kernel 2: MFMA attention with relative_key bias.
// Block = (b, h, 64-row q-tile), 512 threads = 8 waves (2 x 4 over rows x cols).
// Phase A: T[l][jj] = q[l]·demb[l0+jj]  (9 x 64-wide j-tiles, split-bf16 MFMA,
//          stored bf16 in Th[64][584]).
// Phase B: per 64-wide r-tile: QK^T MFMA -> +T gather +mask -> exp (row sums
//          in registers) -> split-bf16 P -> PV MFMA with V^T staged in LDS.
// ---------------------------------------------------------------------------
__global__ __launch_bounds__(512)
void attn_mfma_kernel(const float* __restrict__ Q, const float* __restrict__ K,
                      const float* __restrict__ V, const float* __restrict__ mask,
                      const float* __restrict__ demb, float* __restrict__ out)
{
    const int qt = blockIdx.x, h = blockIdx.y, b = blockIdx.z;
    const int l0 = qt * 64;
    const int tid  = threadIdx.x;
    const int lane = tid & 63;
    const int wave = tid >> 6;   // 0..7
    const int wl = wave >> 2;    // 0..1 : 32-row half
    const int wr = wave & 3;     // 0..3 : 16-col quarter (r / j / d)
    const int fr = lane & 15;
    const int q4 = lane >> 4;

    __shared__ short Th[64][584];                 // bias matrix, bf16, padded
    __shared__ short KhS[64 * 64], KlS[64 * 64];  // K tile (also demb stage)
    __shared__ short VthS[64 * 64], VtlS[64 * 64];// V^T tile
    __shared__ short PhS[64 * 64], PlS[64 * 64];  // P tile
    __shared__ float rowsumw[4][64];
    __shared__ float Ms[64];

    const size_t bh = (size_t)(b * NHH + h) * SS * HDD;
    const float* Qb = Q + bh;
    const float* Kb = K + bh;
    const float* Vb = V + bh;

    const f32x4 fz = {0.f, 0.f, 0.f, 0.f};

    // ---- persistent Q fragments, pre-scaled by 1/8 (exact) ----
    short8 qh[4], ql[4];   // [i*2 + ks]
#pragma unroll
    for (int i = 0; i < 2; i++)
#pragma unroll
        for (int ks = 0; ks < 2; ks++) {
            const float* src = Qb + (size_t)(l0 + wl * 32 + i * 16 + fr) * HDD + ks * 32 + q4 * 8;
            float4 v0 = *(const float4*)src;
            float4 v1 = *(const float4*)(src + 4);
            U4S8 hh, ll;
            split2(v0.x * 0.125f, v0.y * 0.125f, hh.u[0], ll.u[0]);
            split2(v0.z * 0.125f, v0.w * 0.125f, hh.u[1], ll.u[1]);
            split2(v1.x * 0.125f, v1.y * 0.125f, hh.u[2], ll.u[2]);
            split2(v1.z * 0.125f, v1.w * 0.125f, hh.u[3], ll.u[3]);
            qh[i * 2 + ks] = hh.s;
            ql[i * 2 + ks] = ll.s;
        }

    // staging coords (K / demb): 8 threads per row, 8 d each
    const int srow = tid >> 3;
    const int sd   = (tid & 7) * 8;
    const int sel  = srow * 64 + (((sd >> 3) ^ (srow & 7)) << 3);
    const int brow = wr * 16 + fr;   // B-operand row (r / jj / d)

    // ================= Phase A: bias matrix T =================
    for (int jt = 0; jt < 9; jt++) {
        __syncthreads();
        {
            int jrow = l0 + jt * 64 + srow;
            if (jrow > 1022) jrow = 1022;          // clamp (value unused)
            const float* src = demb + (size_t)jrow * HDD + sd;
            float4 v0 = *(const float4*)src;
            float4 v1 = *(const float4*)(src + 4);
            U4S8 hh, ll;
            split2(v0.x, v0.y, hh.u[0], ll.u[0]);
            split2(v0.z, v0.w, hh.u[1], ll.u[1]);
            split2(v1.x, v1.y, hh.u[2], ll.u[2]);
            split2(v1.z, v1.w, hh.u[3], ll.u[3]);
            *(uint4*)&KhS[sel] = hh.v;
            *(uint4*)&KlS[sel] = ll.v;
        }
        __syncthreads();

        f32x4 tacc[2]; tacc[0] = fz; tacc[1] = fz;
#pragma unroll
        for (int ks = 0; ks < 2; ks++) {
            const int bel = brow * 64 + ((((ks * 4) + q4) ^ (brow & 7)) << 3);
            short8 dh = *(const short8*)&KhS[bel];
            short8 dl = *(const short8*)&KlS[bel];
#pragma unroll
            for (int i = 0; i < 2; i++) {
                tacc[i] = __builtin_amdgcn_mfma_f32_16x16x32_bf16(qh[i * 2 + ks], dh, tacc[i], 0, 0, 0);
                tacc[i] = __builtin_amdgcn_mfma_f32_16x16x32_bf16(qh[i * 2 + ks], dl, tacc[i], 0, 0, 0);
                tacc[i] = __builtin_amdgcn_mfma_f32_16x16x32_bf16(ql[i * 2 + ks], dh, tacc[i], 0, 0, 0);
            }
        }
#pragma unroll
        for (int i = 0; i < 2; i++)
#pragma unroll
            for (int r = 0; r < 4; r++)
                Th[wl * 32 + i * 16 + q4 * 4 + r][jt * 64 + brow] = (short)bf16_rne(tacc[i][r]);
    }

    // ================= Phase B: r-tiles =================
    f32x4 ctx[2]; ctx[0] = fz; ctx[1] = fz;
    float rs[2][4] = {{0.f, 0.f, 0.f, 0.f}, {0.f, 0.f, 0.f, 0.f}};

    const int vrow = lane;       // V stage: source row r
    const int vd   = wave * 8;   // V stage: d chunk

    for (int rt = 0; rt < 8; rt++) {
        const int r0 = rt * 64;
        __syncthreads();   // prev PV done; Phase-A reads done (rt==0)

        {   // stage K (row-major, swizzled, split)
            const float* src = Kb + (size_t)(r0 + srow) * HDD + sd;
            float4 v0 = *(const float4*)src;
            float4 v1 = *(const float4*)(src + 4);
            U4S8 hh, ll;
            split2(v0.x, v0.y, hh.u[0], ll.u[0]);
            split2(v0.z, v0.w, hh.u[1], ll.u[1]);
            split2(v1.x, v1.y, hh.u[2], ll.u[2]);
            split2(v1.z, v1.w, hh.u[3], ll.u[3]);
            *(uint4*)&KhS[sel] = hh.v;
            *(uint4*)&KlS[sel] = ll.v;
        }
        {   // stage V transposed [d][r], swizzled, split
            const float* src = Vb + (size_t)(r0 + vrow) * HDD + vd;
            float4 v0 = *(const float4*)src;
            float4 v1 = *(const float4*)(src + 4);
            float vv[8] = {v0.x, v0.y, v0.z, v0.w, v1.x, v1.y, v1.z, v1.w};
#pragma unroll
            for (int u = 0; u < 8; u++) {
                const int d = vd + u;
                unsigned short hb = bf16_tr(vv[u]);
                float lo = vv[u] - bf16f(hb);
                const int el = swel(d, vrow);
                VthS[el] = (short)hb;
                VtlS[el] = (short)bf16_tr(lo);
            }
        }
        if (tid < 64) Ms[tid] = mask[(size_t)b * SS + r0 + tid];
        __syncthreads();

        // ---- QK^T ----
        f32x4 sacc[2]; sacc[0] = fz; sacc[1] = fz;
#pragma unroll
        for (int ks = 0; ks < 2; ks++) {
            const int bel = brow * 64 + ((((ks * 4) + q4) ^ (brow & 7)) << 3);
            short8 kh = *(const short8*)&KhS[bel];
            short8 kl = *(const short8*)&KlS[bel];
#pragma unroll
            for (int i = 0; i < 2; i++) {
                sacc[i] = __builtin_amdgcn_mfma_f32_16x16x32_bf16(qh[i * 2 + ks], kh, sacc[i], 0, 0, 0);
                sacc[i] = __builtin_amdgcn_mfma_f32_16x16x32_bf16(qh[i * 2 + ks], kl, sacc[i], 0, 0, 0);
                sacc[i] = __builtin_amdgcn_mfma_f32_16x16x32_bf16(ql[i * 2 + ks], kh, sacc[i], 0, 0, 0);
            }
        }

        // ---- +T +mask, exp, split-bf16 P ----
#pragma unroll
        for (int i = 0; i < 2; i++)
#pragma unroll
            for (int r = 0; r < 4; r++) {
                const int li = wl * 32 + i * 16 + q4 * 4 + r;
                const int jj = li + 511 - (r0 + brow);
                float logit = sacc[i][r] + bf16f((unsigned short)Th[li][jj]) + Ms[brow];
                float p = __expf(logit);
                rs[i][r] += p;
                unsigned short phb = bf16_tr(p);
                float plo = p - bf16f(phb);
                const int el = swel(li, brow);
                PhS[el] = (short)phb;
                PlS[el] = (short)bf16_tr(plo);
            }
        __syncthreads();

        // ---- PV ----
#pragma unroll
        for (int ks = 0; ks < 2; ks++) {
            const int belv = brow * 64 + ((((ks * 4) + q4) ^ (brow & 7)) << 3);
            short8 vh = *(const short8*)&VthS[belv];
            short8 vl = *(const short8*)&VtlS[belv];
#pragma unroll
            for (int i = 0; i < 2; i++) {
                const int arow = wl * 32 + i * 16 + fr;
                const int ael = arow * 64 + ((((ks * 4) + q4) ^ (arow & 7)) << 3);
                short8 ph = *(const short8*)&PhS[ael];
                short8 pl = *(const short8*)&PlS[ael];
                ctx[i] = __builtin_amdgcn_mfma_f32_16x16x32_bf16(ph, vh, ctx[i], 0, 0, 0);
                ctx[i] = __builtin_amdgcn_mfma_f32_16x16x32_bf16(ph, vl, ctx[i], 0, 0, 0);
                ctx[i] = __builtin_amdgcn_mfma_f32_16x16x32_bf16(pl, vh, ctx[i], 0, 0, 0);
            }
        }
    }

    // ---- row sums: reduce over the 16 col-lanes, combine 4 wr slices ----
#pragma unroll
    for (int i = 0; i < 2; i++)
#pragma unroll
        for (int r = 0; r < 4; r++) {
            float v = rs[i][r];
            v += __shfl_xor(v, 1);
            v += __shfl_xor(v, 2);
            v += __shfl_xor(v, 4);
            v += __shfl_xor(v, 8);
            if (fr == 0) rowsumw[wr][wl * 32 + i * 16 + q4 * 4 + r] = v;
        }
    __syncthreads();

#pragma unroll
    for (int i = 0; i < 2; i++)
#pragma unroll
        for (int r = 0; r < 4; r++) {
            const int li = wl * 32 + i * 16 + q4 * 4 + r;
            const float s = rowsumw[0][li] + rowsumw[1][li] + rowsumw[2][li] + rowsumw[3][li];
            out[((size_t)(b * SS + l0 + li)) * HH + h * HDD + wr * 16 + fr] = ctx[i][r] / s;
        }
}

// ---------------------------------------------------------------------------
extern "C" void kernel_launch(void* const* d_in, const int* in_sizes, int n_in,
                              void* d_out, int out_size, void* d_ws, size_t ws_size,
                              hipStream_t stream)
{
    const float* HS   = (const float*)d_in[0];
    const float* mask = (const float*)d_in[1];
    const float* Wq   = (const float*)d_in[2];
    const float* bq   = (const float*)d_in[3];
    const float* Wk   = (const float*)d_in[4];
    const float* bk   = (const float*)d_in[5];
    const float* Wv   = (const float*)d_in[6];
    const float* bv   = (const float*)d_in[7];
    const float* demb = (const float*)d_in[8];
    float* out = (float*)d_out;

    const size_t per = (size_t)BB * NHH * SS * HDD;
    float* Qw = (float*)d_ws;
    float* Kw = Qw + per;
    float* Vw = Kw + per;

    dim3 gp(24, 32);
    qkv_proj_kernel<<<gp, 256, 0, stream>>>(HS, Wq, bq, Wk, bk, Wv, bv, Qw, Kw, Vw);

    dim3 ga(SS / 64, NHH, BB);
    attn_mfma_kernel<<<ga, 512, 0, stream>>>(Qw, Kw, Vw, mask, demb, out);
}